// Round 7
// baseline (728.003 us; speedup 1.0000x reference)
//
#include <hip/hip_runtime.h>
#include <hip/hip_bf16.h>

// ---------------------------------------------------------------------------
// InterpretableMultiHeadAttention on MI355X (gfx950)
// B=4, S=2048, D=1024, H=16, Dh=64
//
// Round-7 = round-5/6 resubmit (GPU broker timeouts, no data). BISECTION BUILD:
//   - flash_fwd / avg_attn: round-2 bodies VERBATIM (known-good, passed @687us)
//   - gemm_bf: round-3 64x128-tile global_load_lds-staged version (suspect A)
//   - cvt kernels: unchanged (proven)
// If this passes, round-3's swapped flash/avg holds the bug; if it fails, the
// gload16 staging does.
// ---------------------------------------------------------------------------

#define DEVI __device__ __forceinline__

typedef __attribute__((ext_vector_type(8))) short bf16x8;
typedef __attribute__((ext_vector_type(4))) float f32x4;

#define MFMA_BF16(a, b, c) __builtin_amdgcn_mfma_f32_16x16x32_bf16(a, b, c, 0, 0, 0)

constexpr int Bn = 4;
constexpr int Sn = 2048;
constexpr int Dn = 1024;
constexpr int Hn = 16;

DEVI unsigned short f2bf_rn(float x) {
    unsigned u = __float_as_uint(x);
    u += 0x7fffu + ((u >> 16) & 1u);
    return (unsigned short)(u >> 16);
}
DEVI float bf2f(unsigned short h) { return __uint_as_float(((unsigned)h) << 16); }

// XOR swizzles over 8-elem granules (0 bank conflicts measured r1/r2).
DEVI int swz32(int r, int k) { return r * 32 + ((((k >> 3) ^ r) & 3) << 3) + (k & 7); }
DEVI int swz64(int r, int k) { return r * 64 + ((((k >> 3) ^ r) & 7) << 3) + (k & 7); }

// async global->LDS, 16B per lane; dest = uniform base + lane*16
DEVI void gload16(const unsigned short* g, unsigned short* l) {
    __builtin_amdgcn_global_load_lds(
        (const __attribute__((address_space(1))) unsigned int*)g,
        (__attribute__((address_space(3))) unsigned int*)l, 16, 0, 0);
}

// ---------------------------------------------------------------------------
// P0: plain f32 -> bf16 conversion for query/key/value
// ---------------------------------------------------------------------------
__global__ __launch_bounds__(256) void cvt_plain3(
    const float* __restrict__ a, const float* __restrict__ b, const float* __restrict__ c,
    unsigned short* __restrict__ oa, unsigned short* __restrict__ ob,
    unsigned short* __restrict__ oc)
{
    const float* s = blockIdx.y == 0 ? a : blockIdx.y == 1 ? b : c;
    unsigned short* d = blockIdx.y == 0 ? oa : blockIdx.y == 1 ? ob : oc;
    const size_t i = ((size_t)blockIdx.x * 256 + threadIdx.x) * 8;
    const float4 v0 = *reinterpret_cast<const float4*>(s + i);
    const float4 v1 = *reinterpret_cast<const float4*>(s + i + 4);
    const float* p0 = reinterpret_cast<const float*>(&v0);
    const float* p1 = reinterpret_cast<const float*>(&v1);
    bf16x8 o;
#pragma unroll
    for (int j = 0; j < 4; ++j) {
        o[j] = (short)f2bf_rn(p0[j]);
        o[4 + j] = (short)f2bf_rn(p1[j]);
    }
    *reinterpret_cast<bf16x8*>(d + i) = o;
}

// ---------------------------------------------------------------------------
// P1: split f32 -> (hi,lo) bf16 for the four weight matrices
// ---------------------------------------------------------------------------
__global__ __launch_bounds__(256) void cvt_split4(
    const float* __restrict__ w0, const float* __restrict__ w1,
    const float* __restrict__ w2, const float* __restrict__ w3,
    unsigned short* __restrict__ h0, unsigned short* __restrict__ l0,
    unsigned short* __restrict__ h1, unsigned short* __restrict__ l1,
    unsigned short* __restrict__ h2, unsigned short* __restrict__ l2,
    unsigned short* __restrict__ h3, unsigned short* __restrict__ l3)
{
    const int y = blockIdx.y;
    const float* s = y == 0 ? w0 : y == 1 ? w1 : y == 2 ? w2 : w3;
    unsigned short* dh = y == 0 ? h0 : y == 1 ? h1 : y == 2 ? h2 : h3;
    unsigned short* dl = y == 0 ? l0 : y == 1 ? l1 : y == 2 ? l2 : l3;
    const size_t i = ((size_t)blockIdx.x * 256 + threadIdx.x) * 8;
    const float4 v0 = *reinterpret_cast<const float4*>(s + i);
    const float4 v1 = *reinterpret_cast<const float4*>(s + i + 4);
    const float* p0 = reinterpret_cast<const float*>(&v0);
    const float* p1 = reinterpret_cast<const float*>(&v1);
    bf16x8 oh, ol;
#pragma unroll
    for (int j = 0; j < 4; ++j) {
        unsigned short h = f2bf_rn(p0[j]);
        oh[j] = (short)h;
        ol[j] = (short)f2bf_rn(p0[j] - bf2f(h));
        h = f2bf_rn(p1[j]);
        oh[4 + j] = (short)h;
        ol[4 + j] = (short)f2bf_rn(p1[j] - bf2f(h));
    }
    *reinterpret_cast<bf16x8*>(dh + i) = oh;
    *reinterpret_cast<bf16x8*>(dl + i) = ol;
}

// ---------------------------------------------------------------------------
// GEMM (round-3 suspect): C[row,col] = (sum_k X[row,k]*(Whi+Wlo)[col,k]+b)*osc
// Tile 64(M) x 128(N), BK=32, global_load_lds staging, grid (8,128)=1024.
// MODE 0: bf16 [B,H,S,64]   MODE 1: bf16 [B,H,64,S] (V^T)   MODE 2: f32 [M,N]
// ---------------------------------------------------------------------------
template <int MODE>
__global__ __launch_bounds__(256) void gemm_bf(
    const unsigned short* __restrict__ Xbf,
    const unsigned short* __restrict__ Whi, const unsigned short* __restrict__ Wlo,
    const float* __restrict__ bias, float oscale,
    unsigned short* __restrict__ o_bf, float* __restrict__ o_f32)
{
    constexpr int K = Dn;
    __shared__ __align__(16) unsigned short sA[64 * 32];
    __shared__ __align__(16) unsigned short sBh[128 * 32];
    __shared__ __align__(16) unsigned short sBl[128 * 32];

    const int tid = threadIdx.x, lane = tid & 63, w = tid >> 6;
    const int row0 = blockIdx.y * 64, col0 = blockIdx.x * 128;
    const int wn = w * 32;
    const int fr = lane & 15, hi = lane >> 4, kof = hi * 8;

    // staging: granule g -> (row g>>2, pos g&3); content chunk c = (pos^row)&3
    const int gA = w * 64 + lane;
    const int rA = gA >> 2, cA = ((gA & 3) ^ rA) & 3;
    const int gB0 = w * 64 + lane, gB1 = 256 + w * 64 + lane;
    const int rB0 = gB0 >> 2, cB0 = ((gB0 & 3) ^ rB0) & 3;
    const int rB1 = gB1 >> 2, cB1 = ((gB1 & 3) ^ rB1) & 3;

    const unsigned short* pa = Xbf + (size_t)(row0 + rA) * K + cA * 8;
    const unsigned short* pb0h = Whi + (size_t)(col0 + rB0) * K + cB0 * 8;
    const unsigned short* pb1h = Whi + (size_t)(col0 + rB1) * K + cB1 * 8;
    const unsigned short* pb0l = Wlo + (size_t)(col0 + rB0) * K + cB0 * 8;
    const unsigned short* pb1l = Wlo + (size_t)(col0 + rB1) * K + cB1 * 8;

    f32x4 acc[4][2] = {};

    for (int k0 = 0; k0 < K; k0 += 32) {
        gload16(pa + k0, &sA[(w * 64) * 8]);
        gload16(pb0h + k0, &sBh[(w * 64) * 8]);
        gload16(pb1h + k0, &sBh[(256 + w * 64) * 8]);
        gload16(pb0l + k0, &sBl[(w * 64) * 8]);
        gload16(pb1l + k0, &sBl[(256 + w * 64) * 8]);
        __syncthreads();

        bf16x8 fa[4], fbh[2], fbl[2];
#pragma unroll
        for (int m = 0; m < 4; ++m) fa[m] = *(const bf16x8*)&sA[swz32(m * 16 + fr, kof)];
#pragma unroll
        for (int n = 0; n < 2; ++n) {
            const int ib = swz32(wn + n * 16 + fr, kof);
            fbh[n] = *(const bf16x8*)&sBh[ib];
            fbl[n] = *(const bf16x8*)&sBl[ib];
        }
#pragma unroll
        for (int m = 0; m < 4; ++m)
#pragma unroll
            for (int n = 0; n < 2; ++n) {
                acc[m][n] = MFMA_BF16(fa[m], fbh[n], acc[m][n]);
                acc[m][n] = MFMA_BF16(fa[m], fbl[n], acc[m][n]);
            }
        __syncthreads();
    }

    float bv_[2];
#pragma unroll
    for (int n = 0; n < 2; ++n) bv_[n] = bias[col0 + wn + n * 16 + fr];

#pragma unroll
    for (int m = 0; m < 4; ++m)
#pragma unroll
        for (int n = 0; n < 2; ++n)
#pragma unroll
            for (int r = 0; r < 4; ++r) {
                const int row = row0 + m * 16 + hi * 4 + r;
                const int col = col0 + wn + n * 16 + fr;
                float v = acc[m][n][r] + bv_[n];
                if (MODE == 0) {
                    v *= oscale;
                    const int bb = row >> 11, s = row & 2047;
                    const int hh = col >> 6, dh = col & 63;
                    o_bf[((size_t)(bb * Hn + hh) * Sn + s) * 64 + dh] = f2bf_rn(v);
                } else if (MODE == 1) {
                    const int bb = row >> 11, s = row & 2047;
                    const int hh = col >> 6, dh = col & 63;
                    o_bf[((size_t)(bb * Hn + hh) * 64 + dh) * Sn + s] = f2bf_rn(v);
                } else {
                    o_f32[(size_t)row * Dn + col] = v;
                }
            }
}

// ---------------------------------------------------------------------------
// K2: flash attention — ROUND-2 BODY VERBATIM (known good).
// One block = (b, h, qtile64), 4 waves x 16 rows.
// ---------------------------------------------------------------------------
__global__ __launch_bounds__(256) void flash_fwd(
    const unsigned short* __restrict__ Qbf, const unsigned short* __restrict__ Kbf,
    const unsigned short* __restrict__ Vt,
    unsigned short* __restrict__ attn_bf, float* __restrict__ m_ws, float* __restrict__ l_ws)
{
    __shared__ __align__(16) unsigned short kh_l[64 * 64];
    __shared__ __align__(16) unsigned short vt_l[64 * 64];
    __shared__ __align__(16) unsigned short p_l[4 * 16 * 64];

    const int tid = threadIdx.x, lane = tid & 63, w = tid >> 6;
    const int qt = blockIdx.x & 31;
    const int h = (blockIdx.x >> 5) & 15;
    const int b = blockIdx.x >> 9;
    const int fr = lane & 15, kof = (lane >> 4) * 8;
    const size_t head = (size_t)(b * Hn + h) * Sn;
    const int qbase = qt * 64;
    const int qrow = qbase + w * 16 + fr;

    bf16x8 aq[2];
    {
        const unsigned short* qp = Qbf + (head + qrow) * 64;
        aq[0] = *(const bf16x8*)(qp + kof);
        aq[1] = *(const bf16x8*)(qp + 32 + kof);
    }

    float m_r[4] = {-1e30f, -1e30f, -1e30f, -1e30f};
    float l_r[4] = {0.f, 0.f, 0.f, 0.f};
    f32x4 o[4] = {};

    for (int kb = 0; kb < Sn; kb += 64) {
#pragma unroll
        for (int j = 0; j < 2; ++j) {
            const int u = tid + j * 256;
            const int r = u >> 3, sg = (u & 7) * 8;
            *(bf16x8*)&kh_l[swz64(r, sg)] = *(const bf16x8*)(Kbf + (head + kb + r) * 64 + sg);
            *(bf16x8*)&vt_l[swz64(r, sg)] =
                *(const bf16x8*)(Vt + ((size_t)(b * Hn + h) * 64 + r) * Sn + kb + sg);
        }
        __syncthreads();

        f32x4 sc[4] = {};
#pragma unroll
        for (int n = 0; n < 4; ++n) {
            const int kr = n * 16 + fr;
#pragma unroll
            for (int ks = 0; ks < 2; ++ks) {
                const bf16x8 bh = *(const bf16x8*)&kh_l[swz64(kr, ks * 32 + kof)];
                sc[n] = MFMA_BF16(aq[ks], bh, sc[n]);
            }
        }
#pragma unroll
        for (int n = 0; n < 4; ++n) sc[n] *= 0.125f;

        float mnew[4];
        bool grow = false;
#pragma unroll
        for (int r = 0; r < 4; ++r) {
            float rm = fmaxf(fmaxf(sc[0][r], sc[1][r]), fmaxf(sc[2][r], sc[3][r]));
            rm = fmaxf(rm, __shfl_xor(rm, 1));
            rm = fmaxf(rm, __shfl_xor(rm, 2));
            rm = fmaxf(rm, __shfl_xor(rm, 4));
            rm = fmaxf(rm, __shfl_xor(rm, 8));
            mnew[r] = fmaxf(m_r[r], rm);
            grow = grow || (mnew[r] > m_r[r]);
        }
        if (__any((int)grow)) {
#pragma unroll
            for (int r = 0; r < 4; ++r) {
                const float scale_ = __expf(m_r[r] - mnew[r]);
#pragma unroll
                for (int n = 0; n < 4; ++n) o[n][r] *= scale_;
                l_r[r] *= scale_;
                m_r[r] = mnew[r];
            }
        }

        float rsum[4] = {0.f, 0.f, 0.f, 0.f};
#pragma unroll
        for (int n = 0; n < 4; ++n)
#pragma unroll
            for (int r = 0; r < 4; ++r) {
                const float p = __expf(sc[n][r] - m_r[r]);
                rsum[r] += p;
                p_l[w * 1024 + swz64((lane >> 4) * 4 + r, n * 16 + fr)] = f2bf_rn(p);
            }
#pragma unroll
        for (int r = 0; r < 4; ++r) {
            float t = rsum[r];
            t += __shfl_xor(t, 1);
            t += __shfl_xor(t, 2);
            t += __shfl_xor(t, 4);
            t += __shfl_xor(t, 8);
            l_r[r] += t;
        }

        const bf16x8 pa0 = *(const bf16x8*)&p_l[w * 1024 + swz64(fr, kof)];
        const bf16x8 pa1 = *(const bf16x8*)&p_l[w * 1024 + swz64(fr, 32 + kof)];
#pragma unroll
        for (int n = 0; n < 4; ++n) {
            const bf16x8 bv0 = *(const bf16x8*)&vt_l[swz64(n * 16 + fr, kof)];
            const bf16x8 bv1 = *(const bf16x8*)&vt_l[swz64(n * 16 + fr, 32 + kof)];
            o[n] = MFMA_BF16(pa0, bv0, o[n]);
            o[n] = MFMA_BF16(pa1, bv1, o[n]);
        }
        __syncthreads();
    }

#pragma unroll
    for (int r = 0; r < 4; ++r) {
        const float inv = 1.f / l_r[r];
        const int row_ = qbase + w * 16 + (lane >> 4) * 4 + r;
#pragma unroll
        for (int n = 0; n < 4; ++n)
            attn_bf[((size_t)(b * Sn + row_)) * Dn + h * 64 + n * 16 + fr] =
                f2bf_rn(o[n][r] * inv);
    }
    if (fr == 0) {
#pragma unroll
        for (int r = 0; r < 4; ++r) {
            const int row_ = qbase + w * 16 + (lane >> 4) * 4 + r;
            m_ws[head + row_] = m_r[r];
            l_ws[head + row_] = l_r[r];
        }
    }
}

// ---------------------------------------------------------------------------
// K3: avg_attention — ROUND-2 BODY VERBATIM (known good).
// ---------------------------------------------------------------------------
__global__ __launch_bounds__(256) void avg_attn_kernel(
    const unsigned short* __restrict__ Qbf, const unsigned short* __restrict__ Kbf,
    const float* __restrict__ m_ws, const float* __restrict__ l_ws,
    float* __restrict__ avg)
{
    __shared__ __align__(16) unsigned short kh_l[64 * 64];

    const int tid = threadIdx.x, lane = tid & 63, w = tid >> 6;
    const int kt = blockIdx.x & 31;
    const int qt = (blockIdx.x >> 5) & 31;
    const int b = blockIdx.x >> 10;
    const int fr = lane & 15, kof = (lane >> 4) * 8;
    const int qbase = qt * 64, kbase = kt * 64;
    const int qrow = qbase + w * 16 + fr;

    f32x4 facc[4] = {};

    for (int h = 0; h < Hn; ++h) {
        const size_t head = (size_t)(b * Hn + h) * Sn;
#pragma unroll
        for (int j = 0; j < 2; ++j) {
            const int u = tid + j * 256;
            const int r = u >> 3, sg = (u & 7) * 8;
            *(bf16x8*)&kh_l[swz64(r, sg)] = *(const bf16x8*)(Kbf + (head + kbase + r) * 64 + sg);
        }
        __syncthreads();

        const unsigned short* qp = Qbf + (head + qrow) * 64;
        const bf16x8 aq0 = *(const bf16x8*)(qp + kof);
        const bf16x8 aq1 = *(const bf16x8*)(qp + 32 + kof);

        f32x4 sc[4] = {};
#pragma unroll
        for (int n = 0; n < 4; ++n) {
            const int kr = n * 16 + fr;
            const bf16x8 bh0 = *(const bf16x8*)&kh_l[swz64(kr, kof)];
            const bf16x8 bh1 = *(const bf16x8*)&kh_l[swz64(kr, 32 + kof)];
            sc[n] = MFMA_BF16(aq0, bh0, sc[n]);
            sc[n] = MFMA_BF16(aq1, bh1, sc[n]);
        }
#pragma unroll
        for (int r = 0; r < 4; ++r) {
            const int row_ = qbase + w * 16 + (lane >> 4) * 4 + r;
            const float mm = m_ws[head + row_];
            const float li = 0.0625f / l_ws[head + row_];
#pragma unroll
            for (int n = 0; n < 4; ++n) {
                const float ss = sc[n][r] * 0.125f;
                facc[n][r] += __expf(ss - mm) * li;
            }
        }
        __syncthreads();
    }

#pragma unroll
    for (int r = 0; r < 4; ++r) {
        const int row_ = qbase + w * 16 + (lane >> 4) * 4 + r;
#pragma unroll
        for (int n = 0; n < 4; ++n)
            avg[((size_t)(b * Sn + row_)) * Sn + kbase + n * 16 + fr] = facc[n][r];
    }
}

// ---------------------------------------------------------------------------
extern "C" void kernel_launch(void* const* d_in, const int* in_sizes, int n_in,
                              void* d_out, int out_size, void* d_ws, size_t ws_size,
                              hipStream_t stream)
{
    const float* query = (const float*)d_in[0];
    const float* key_ = (const float*)d_in[1];
    const float* value = (const float*)d_in[2];
    const float* Wq = (const float*)d_in[3];
    const float* bq = (const float*)d_in[4];
    const float* Wk = (const float*)d_in[5];
    const float* bk = (const float*)d_in[6];
    const float* Wv = (const float*)d_in[7];
    const float* bv = (const float*)d_in[8];
    const float* Wo = (const float*)d_in[9];
    const float* bo = (const float*)d_in[10];

    const size_t QE = (size_t)Bn * Hn * Sn * 64;  // 8,388,608
    const size_t WE = (size_t)Dn * Dn;            // 1,048,576

    unsigned short* Qbf = (unsigned short*)d_ws;
    unsigned short* Kbf = Qbf + QE;
    unsigned short* Vt = Kbf + QE;
    unsigned short* Xq = Vt + QE;  // reused as attn_bf after gemm Q
    unsigned short* Xk = Xq + QE;
    unsigned short* Xv = Xk + QE;
    unsigned short* Wqh = Xv + QE;
    unsigned short* Wql = Wqh + WE;
    unsigned short* Wkh = Wql + WE;
    unsigned short* Wkl = Wkh + WE;
    unsigned short* Wvh = Wkl + WE;
    unsigned short* Wvl = Wvh + WE;
    unsigned short* Woh = Wvl + WE;
    unsigned short* Wol = Woh + WE;
    float* m_ws = (float*)(Wol + WE);
    float* l_ws = m_ws + (size_t)Bn * Hn * Sn;
    unsigned short* attn_bf = Xq;

    float* out0 = (float*)d_out;
    float* avg = out0 + (size_t)Bn * Sn * Dn;

    cvt_plain3<<<dim3(4096, 3), 256, 0, stream>>>(query, key_, value, Xq, Xk, Xv);
    cvt_split4<<<dim3(512, 4), 256, 0, stream>>>(Wq, Wk, Wv, Wo, Wqh, Wql, Wkh, Wkl,
                                                 Wvh, Wvl, Woh, Wol);

    const dim3 gg(8, 128), bb(256);
    gemm_bf<0><<<gg, bb, 0, stream>>>(Xq, Wqh, Wql, bq, 1.0f, Qbf, nullptr);
    gemm_bf<0><<<gg, bb, 0, stream>>>(Xk, Wkh, Wkl, bk, 1.0f, Kbf, nullptr);
    gemm_bf<1><<<gg, bb, 0, stream>>>(Xv, Wvh, Wvl, bv, 1.0f, Vt, nullptr);
    flash_fwd<<<dim3(Bn * Hn * (Sn / 64)), bb, 0, stream>>>(Qbf, Kbf, Vt, attn_bf,
                                                            m_ws, l_ws);
    avg_attn_kernel<<<dim3(Bn * 32 * 32), bb, 0, stream>>>(Qbf, Kbf, m_ws, l_ws, avg);
    gemm_bf<2><<<gg, bb, 0, stream>>>(attn_bf, Woh, Wol, bo, 1.0f, nullptr, out0);
}

// Round 8
// 662.780 us; speedup vs baseline: 1.0984x; 1.0984x over previous
//
#include <hip/hip_runtime.h>
#include <hip/hip_bf16.h>

// ---------------------------------------------------------------------------
// InterpretableMultiHeadAttention on MI355X (gfx950)
// B=4, S=2048, D=1024, H=16, Dh=64
//
// Round-8: recombination of PROVEN pieces only.
//   - gemm_bf: 128x128 tile (round-2-proven read side) + gload16 staging
//              (bisect-proven write side). oscale folds 0.125*log2e into Q.
//   - flash_fwd: round-2 compute VERBATIM + gload16 double-buffered K/V
//                staging (1 barrier/tile) + exp2-domain softmax.
//   - avg_attn: round-2 compute + gload16 staging lines + exp2 domain.
//     (scores remain bitwise-identical to flash: same MFMA sequence.)
// ---------------------------------------------------------------------------

#define DEVI __device__ __forceinline__

typedef __attribute__((ext_vector_type(8))) short bf16x8;
typedef __attribute__((ext_vector_type(4))) float f32x4;

#define MFMA_BF16(a, b, c) __builtin_amdgcn_mfma_f32_16x16x32_bf16(a, b, c, 0, 0, 0)

constexpr int Bn = 4;
constexpr int Sn = 2048;
constexpr int Dn = 1024;
constexpr int Hn = 16;

DEVI unsigned short f2bf_rn(float x) {
    unsigned u = __float_as_uint(x);
    u += 0x7fffu + ((u >> 16) & 1u);
    return (unsigned short)(u >> 16);
}
DEVI float bf2f(unsigned short h) { return __uint_as_float(((unsigned)h) << 16); }

// XOR swizzles over 8-elem granules (0 bank conflicts measured r1/r2/r7).
DEVI int swz32(int r, int k) { return r * 32 + ((((k >> 3) ^ r) & 3) << 3) + (k & 7); }
DEVI int swz64(int r, int k) { return r * 64 + ((((k >> 3) ^ r) & 7) << 3) + (k & 7); }

// async global->LDS, 16B per lane; dest = wave-uniform base + lane*16
DEVI void gload16(const unsigned short* g, unsigned short* l) {
    __builtin_amdgcn_global_load_lds(
        (const __attribute__((address_space(1))) unsigned int*)g,
        (__attribute__((address_space(3))) unsigned int*)l, 16, 0, 0);
}

// ---------------------------------------------------------------------------
// P0: plain f32 -> bf16 conversion for query/key/value
// ---------------------------------------------------------------------------
__global__ __launch_bounds__(256) void cvt_plain3(
    const float* __restrict__ a, const float* __restrict__ b, const float* __restrict__ c,
    unsigned short* __restrict__ oa, unsigned short* __restrict__ ob,
    unsigned short* __restrict__ oc)
{
    const float* s = blockIdx.y == 0 ? a : blockIdx.y == 1 ? b : c;
    unsigned short* d = blockIdx.y == 0 ? oa : blockIdx.y == 1 ? ob : oc;
    const size_t i = ((size_t)blockIdx.x * 256 + threadIdx.x) * 8;
    const float4 v0 = *reinterpret_cast<const float4*>(s + i);
    const float4 v1 = *reinterpret_cast<const float4*>(s + i + 4);
    const float* p0 = reinterpret_cast<const float*>(&v0);
    const float* p1 = reinterpret_cast<const float*>(&v1);
    bf16x8 o;
#pragma unroll
    for (int j = 0; j < 4; ++j) {
        o[j] = (short)f2bf_rn(p0[j]);
        o[4 + j] = (short)f2bf_rn(p1[j]);
    }
    *reinterpret_cast<bf16x8*>(d + i) = o;
}

// ---------------------------------------------------------------------------
// P1: split f32 -> (hi,lo) bf16 for the four weight matrices
// ---------------------------------------------------------------------------
__global__ __launch_bounds__(256) void cvt_split4(
    const float* __restrict__ w0, const float* __restrict__ w1,
    const float* __restrict__ w2, const float* __restrict__ w3,
    unsigned short* __restrict__ h0, unsigned short* __restrict__ l0,
    unsigned short* __restrict__ h1, unsigned short* __restrict__ l1,
    unsigned short* __restrict__ h2, unsigned short* __restrict__ l2,
    unsigned short* __restrict__ h3, unsigned short* __restrict__ l3)
{
    const int y = blockIdx.y;
    const float* s = y == 0 ? w0 : y == 1 ? w1 : y == 2 ? w2 : w3;
    unsigned short* dh = y == 0 ? h0 : y == 1 ? h1 : y == 2 ? h2 : h3;
    unsigned short* dl = y == 0 ? l0 : y == 1 ? l1 : y == 2 ? l2 : l3;
    const size_t i = ((size_t)blockIdx.x * 256 + threadIdx.x) * 8;
    const float4 v0 = *reinterpret_cast<const float4*>(s + i);
    const float4 v1 = *reinterpret_cast<const float4*>(s + i + 4);
    const float* p0 = reinterpret_cast<const float*>(&v0);
    const float* p1 = reinterpret_cast<const float*>(&v1);
    bf16x8 oh, ol;
#pragma unroll
    for (int j = 0; j < 4; ++j) {
        unsigned short h = f2bf_rn(p0[j]);
        oh[j] = (short)h;
        ol[j] = (short)f2bf_rn(p0[j] - bf2f(h));
        h = f2bf_rn(p1[j]);
        oh[4 + j] = (short)h;
        ol[4 + j] = (short)f2bf_rn(p1[j] - bf2f(h));
    }
    *reinterpret_cast<bf16x8*>(dh + i) = oh;
    *reinterpret_cast<bf16x8*>(dl + i) = ol;
}

// ---------------------------------------------------------------------------
// GEMM: C[row,col] = (sum_k X[row,k]*(Whi+Wlo)[col,k] + bias[col]) * oscale
// Tile 128x128, BK=32, gload16 staging (granule ^r swizzle, bisect-proven),
// read side = round-2's swz32 fragments (proven). Grid (8,64) = 512 blocks.
// MODE 0: bf16 [B,H,S,64]  MODE 1: bf16 [B,H,64,S] (V^T)  MODE 2: f32 [M,N]
// ---------------------------------------------------------------------------
template <int MODE>
__global__ __launch_bounds__(256) void gemm_bf(
    const unsigned short* __restrict__ Xbf,
    const unsigned short* __restrict__ Whi, const unsigned short* __restrict__ Wlo,
    const float* __restrict__ bias, float oscale,
    unsigned short* __restrict__ o_bf, float* __restrict__ o_f32)
{
    constexpr int K = Dn;
    __shared__ __align__(16) unsigned short sA[128 * 32];
    __shared__ __align__(16) unsigned short sBh[128 * 32];
    __shared__ __align__(16) unsigned short sBl[128 * 32];

    const int tid = threadIdx.x, lane = tid & 63, w = tid >> 6;
    const int row0 = blockIdx.y * 128, col0 = blockIdx.x * 128;
    const int wm = (w >> 1) * 64, wn = (w & 1) * 64;
    const int fr = lane & 15, hi = lane >> 4, kof = hi * 8;

    // staging: granule g -> (row g>>2, slot g&3); content chunk c = (slot^row)&3
    const int g0 = tid, g1 = tid + 256;
    const int r0 = g0 >> 2, c0 = ((g0 & 3) ^ r0) & 3;
    const int r1 = g1 >> 2, c1 = ((g1 & 3) ^ r1) & 3;

    const unsigned short* pa0 = Xbf + (size_t)(row0 + r0) * K + c0 * 8;
    const unsigned short* pa1 = Xbf + (size_t)(row0 + r1) * K + c1 * 8;
    const unsigned short* pbh0 = Whi + (size_t)(col0 + r0) * K + c0 * 8;
    const unsigned short* pbh1 = Whi + (size_t)(col0 + r1) * K + c1 * 8;
    const unsigned short* pbl0 = Wlo + (size_t)(col0 + r0) * K + c0 * 8;
    const unsigned short* pbl1 = Wlo + (size_t)(col0 + r1) * K + c1 * 8;

    f32x4 acc[4][4] = {};

    for (int k0 = 0; k0 < K; k0 += 32) {
        gload16(pa0 + k0, &sA[(w * 64) * 8]);
        gload16(pa1 + k0, &sA[(256 + w * 64) * 8]);
        gload16(pbh0 + k0, &sBh[(w * 64) * 8]);
        gload16(pbh1 + k0, &sBh[(256 + w * 64) * 8]);
        gload16(pbl0 + k0, &sBl[(w * 64) * 8]);
        gload16(pbl1 + k0, &sBl[(256 + w * 64) * 8]);
        __syncthreads();

        bf16x8 fa[4], fbh[4], fbl[4];
#pragma unroll
        for (int m = 0; m < 4; ++m) fa[m] = *(const bf16x8*)&sA[swz32(wm + m * 16 + fr, kof)];
#pragma unroll
        for (int n = 0; n < 4; ++n) {
            const int ib = swz32(wn + n * 16 + fr, kof);
            fbh[n] = *(const bf16x8*)&sBh[ib];
            fbl[n] = *(const bf16x8*)&sBl[ib];
        }
#pragma unroll
        for (int m = 0; m < 4; ++m)
#pragma unroll
            for (int n = 0; n < 4; ++n) {
                acc[m][n] = MFMA_BF16(fa[m], fbh[n], acc[m][n]);
                acc[m][n] = MFMA_BF16(fa[m], fbl[n], acc[m][n]);
            }
        __syncthreads();
    }

    float bv_[4];
#pragma unroll
    for (int n = 0; n < 4; ++n) bv_[n] = bias[col0 + wn + n * 16 + fr];

#pragma unroll
    for (int m = 0; m < 4; ++m)
#pragma unroll
        for (int n = 0; n < 4; ++n)
#pragma unroll
            for (int r = 0; r < 4; ++r) {
                const int row = row0 + wm + m * 16 + hi * 4 + r;
                const int col = col0 + wn + n * 16 + fr;
                float v = acc[m][n][r] + bv_[n];
                if (MODE == 0) {
                    v *= oscale;
                    const int bb = row >> 11, s = row & 2047;
                    const int hh = col >> 6, dh = col & 63;
                    o_bf[((size_t)(bb * Hn + hh) * Sn + s) * 64 + dh] = f2bf_rn(v);
                } else if (MODE == 1) {
                    const int bb = row >> 11, s = row & 2047;
                    const int hh = col >> 6, dh = col & 63;
                    o_bf[((size_t)(bb * Hn + hh) * 64 + dh) * Sn + s] = f2bf_rn(v);
                } else {
                    o_f32[(size_t)row * Dn + col] = v;
                }
            }
}

// ---------------------------------------------------------------------------
// K2: flash attention. Round-2 compute VERBATIM; staging switched to gload16
// double-buffer (1 barrier/tile); exp2-domain (0.125*log2e folded into Q).
// m_ws now stores the log2-domain running max.
// ---------------------------------------------------------------------------
__global__ __launch_bounds__(256) void flash_fwd(
    const unsigned short* __restrict__ Qbf, const unsigned short* __restrict__ Kbf,
    const unsigned short* __restrict__ Vt,
    unsigned short* __restrict__ attn_bf, float* __restrict__ m_ws, float* __restrict__ l_ws)
{
    __shared__ __align__(16) unsigned short kh_l[2][64 * 64];
    __shared__ __align__(16) unsigned short vt_l[2][64 * 64];
    __shared__ __align__(16) unsigned short p_l[4 * 16 * 64];

    const int tid = threadIdx.x, lane = tid & 63, w = tid >> 6;
    const int qt = blockIdx.x & 31;
    const int h = (blockIdx.x >> 5) & 15;
    const int b = blockIdx.x >> 9;
    const int fr = lane & 15, kof = (lane >> 4) * 8;
    const size_t head = (size_t)(b * Hn + h) * Sn;
    const int qbase = qt * 64;
    const int qrow = qbase + w * 16 + fr;

    // staging addresses: granule g -> (row g>>3, slot g&7); chunk = (slot^row)&7
    const int gS0 = w * 64 + lane, gS1 = 256 + w * 64 + lane;
    const int rS0 = gS0 >> 3, cS0 = ((gS0 & 7) ^ rS0) & 7;
    const int rS1 = gS1 >> 3, cS1 = ((gS1 & 7) ^ rS1) & 7;
    const unsigned short* kp0 = Kbf + (head + rS0) * 64 + cS0 * 8;
    const unsigned short* kp1 = Kbf + (head + rS1) * 64 + cS1 * 8;
    const unsigned short* vp0 = Vt + ((size_t)(b * Hn + h) * 64 + rS0) * Sn + cS0 * 8;
    const unsigned short* vp1 = Vt + ((size_t)(b * Hn + h) * 64 + rS1) * Sn + cS1 * 8;

    bf16x8 aq[2];
    {
        const unsigned short* qp = Qbf + (head + qrow) * 64;
        aq[0] = *(const bf16x8*)(qp + kof);
        aq[1] = *(const bf16x8*)(qp + 32 + kof);
    }

    float m_r[4] = {-1e30f, -1e30f, -1e30f, -1e30f};
    float l_r[4] = {0.f, 0.f, 0.f, 0.f};
    f32x4 o[4] = {};
    int cur = 0;

    // prologue: stage tile 0
    gload16(kp0, &kh_l[0][(w * 64) * 8]);
    gload16(kp1, &kh_l[0][(256 + w * 64) * 8]);
    gload16(vp0, &vt_l[0][(w * 64) * 8]);
    gload16(vp1, &vt_l[0][(256 + w * 64) * 8]);
    __syncthreads();

    for (int kb = 0; kb < Sn; kb += 64) {
        if (kb + 64 < Sn) {  // stage next tile into the other buffer (async)
            const int nb = cur ^ 1;
            gload16(kp0 + (size_t)(kb + 64) * 64, &kh_l[nb][(w * 64) * 8]);
            gload16(kp1 + (size_t)(kb + 64) * 64, &kh_l[nb][(256 + w * 64) * 8]);
            gload16(vp0 + kb + 64, &vt_l[nb][(w * 64) * 8]);
            gload16(vp1 + kb + 64, &vt_l[nb][(256 + w * 64) * 8]);
        }

        f32x4 sc[4] = {};
#pragma unroll
        for (int n = 0; n < 4; ++n) {
            const int kr = n * 16 + fr;
#pragma unroll
            for (int ks = 0; ks < 2; ++ks) {
                const bf16x8 bh = *(const bf16x8*)&kh_l[cur][swz64(kr, ks * 32 + kof)];
                sc[n] = MFMA_BF16(aq[ks], bh, sc[n]);
            }
        }
        // sc is already in log2 domain (0.125*log2e folded into Q)

        float mnew[4];
        bool grow = false;
#pragma unroll
        for (int r = 0; r < 4; ++r) {
            float rm = fmaxf(fmaxf(sc[0][r], sc[1][r]), fmaxf(sc[2][r], sc[3][r]));
            rm = fmaxf(rm, __shfl_xor(rm, 1));
            rm = fmaxf(rm, __shfl_xor(rm, 2));
            rm = fmaxf(rm, __shfl_xor(rm, 4));
            rm = fmaxf(rm, __shfl_xor(rm, 8));
            mnew[r] = fmaxf(m_r[r], rm);
            grow = grow || (mnew[r] > m_r[r]);
        }
        if (__any((int)grow)) {  // exact skip: only when no row's max grew
#pragma unroll
            for (int r = 0; r < 4; ++r) {
                const float scale_ = __builtin_amdgcn_exp2f(m_r[r] - mnew[r]);
#pragma unroll
                for (int n = 0; n < 4; ++n) o[n][r] *= scale_;
                l_r[r] *= scale_;
                m_r[r] = mnew[r];
            }
        }

        float rsum[4] = {0.f, 0.f, 0.f, 0.f};
#pragma unroll
        for (int n = 0; n < 4; ++n)
#pragma unroll
            for (int r = 0; r < 4; ++r) {
                const float p = __builtin_amdgcn_exp2f(sc[n][r] - m_r[r]);
                rsum[r] += p;
                p_l[w * 1024 + swz64((lane >> 4) * 4 + r, n * 16 + fr)] = f2bf_rn(p);
            }
#pragma unroll
        for (int r = 0; r < 4; ++r) {
            float t = rsum[r];
            t += __shfl_xor(t, 1);
            t += __shfl_xor(t, 2);
            t += __shfl_xor(t, 4);
            t += __shfl_xor(t, 8);
            l_r[r] += t;
        }

        const bf16x8 pa0 = *(const bf16x8*)&p_l[w * 1024 + swz64(fr, kof)];
        const bf16x8 pa1 = *(const bf16x8*)&p_l[w * 1024 + swz64(fr, 32 + kof)];
#pragma unroll
        for (int n = 0; n < 4; ++n) {
            const bf16x8 bv0 = *(const bf16x8*)&vt_l[cur][swz64(n * 16 + fr, kof)];
            const bf16x8 bv1 = *(const bf16x8*)&vt_l[cur][swz64(n * 16 + fr, 32 + kof)];
            o[n] = MFMA_BF16(pa0, bv0, o[n]);
            o[n] = MFMA_BF16(pa1, bv1, o[n]);
        }
        __syncthreads();  // drains vmcnt(0): next tile landed; cur reads done
        cur ^= 1;
    }

#pragma unroll
    for (int r = 0; r < 4; ++r) {
        const float inv = 1.f / l_r[r];
        const int row_ = qbase + w * 16 + (lane >> 4) * 4 + r;
#pragma unroll
        for (int n = 0; n < 4; ++n)
            attn_bf[((size_t)(b * Sn + row_)) * Dn + h * 64 + n * 16 + fr] =
                f2bf_rn(o[n][r] * inv);
    }
    if (fr == 0) {
#pragma unroll
        for (int r = 0; r < 4; ++r) {
            const int row_ = qbase + w * 16 + (lane >> 4) * 4 + r;
            m_ws[head + row_] = m_r[r];  // log2 domain
            l_ws[head + row_] = l_r[r];
        }
    }
}

// ---------------------------------------------------------------------------
// K3: avg_attention. Round-2 compute; staging via gload16; exp2 domain.
// Scores bitwise-identical to flash (same MFMA sequence on same data).
// ---------------------------------------------------------------------------
__global__ __launch_bounds__(256) void avg_attn_kernel(
    const unsigned short* __restrict__ Qbf, const unsigned short* __restrict__ Kbf,
    const float* __restrict__ m_ws, const float* __restrict__ l_ws,
    float* __restrict__ avg)
{
    __shared__ __align__(16) unsigned short kh_l[64 * 64];

    const int tid = threadIdx.x, lane = tid & 63, w = tid >> 6;
    const int kt = blockIdx.x & 31;
    const int qt = (blockIdx.x >> 5) & 31;
    const int b = blockIdx.x >> 10;
    const int fr = lane & 15, kof = (lane >> 4) * 8;
    const int qbase = qt * 64, kbase = kt * 64;
    const int qrow = qbase + w * 16 + fr;

    const int gS0 = w * 64 + lane, gS1 = 256 + w * 64 + lane;
    const int rS0 = gS0 >> 3, cS0 = ((gS0 & 7) ^ rS0) & 7;
    const int rS1 = gS1 >> 3, cS1 = ((gS1 & 7) ^ rS1) & 7;

    f32x4 facc[4] = {};

    for (int h = 0; h < Hn; ++h) {
        const size_t head = (size_t)(b * Hn + h) * Sn;
        gload16(Kbf + (head + kbase + rS0) * 64 + cS0 * 8, &kh_l[(w * 64) * 8]);
        gload16(Kbf + (head + kbase + rS1) * 64 + cS1 * 8, &kh_l[(256 + w * 64) * 8]);
        __syncthreads();

        const unsigned short* qp = Qbf + (head + qrow) * 64;
        const bf16x8 aq0 = *(const bf16x8*)(qp + kof);
        const bf16x8 aq1 = *(const bf16x8*)(qp + 32 + kof);

        f32x4 sc[4] = {};
#pragma unroll
        for (int n = 0; n < 4; ++n) {
            const int kr = n * 16 + fr;
            const bf16x8 bh0 = *(const bf16x8*)&kh_l[swz64(kr, kof)];
            const bf16x8 bh1 = *(const bf16x8*)&kh_l[swz64(kr, 32 + kof)];
            sc[n] = MFMA_BF16(aq0, bh0, sc[n]);
            sc[n] = MFMA_BF16(aq1, bh1, sc[n]);
        }
#pragma unroll
        for (int r = 0; r < 4; ++r) {
            const int row_ = qbase + w * 16 + (lane >> 4) * 4 + r;
            const float mm = m_ws[head + row_];  // log2 domain
            const float li = 0.0625f / l_ws[head + row_];
#pragma unroll
            for (int n = 0; n < 4; ++n)
                facc[n][r] += __builtin_amdgcn_exp2f(sc[n][r] - mm) * li;
        }
        __syncthreads();
    }

#pragma unroll
    for (int r = 0; r < 4; ++r) {
        const int row_ = qbase + w * 16 + (lane >> 4) * 4 + r;
#pragma unroll
        for (int n = 0; n < 4; ++n)
            avg[((size_t)(b * Sn + row_)) * Sn + kbase + n * 16 + fr] = facc[n][r];
    }
}

// ---------------------------------------------------------------------------
extern "C" void kernel_launch(void* const* d_in, const int* in_sizes, int n_in,
                              void* d_out, int out_size, void* d_ws, size_t ws_size,
                              hipStream_t stream)
{
    const float* query = (const float*)d_in[0];
    const float* key_ = (const float*)d_in[1];
    const float* value = (const float*)d_in[2];
    const float* Wq = (const float*)d_in[3];
    const float* bq = (const float*)d_in[4];
    const float* Wk = (const float*)d_in[5];
    const float* bk = (const float*)d_in[6];
    const float* Wv = (const float*)d_in[7];
    const float* bv = (const float*)d_in[8];
    const float* Wo = (const float*)d_in[9];
    const float* bo = (const float*)d_in[10];

    const size_t QE = (size_t)Bn * Hn * Sn * 64;  // 8,388,608
    const size_t WE = (size_t)Dn * Dn;            // 1,048,576

    unsigned short* Qbf = (unsigned short*)d_ws;
    unsigned short* Kbf = Qbf + QE;
    unsigned short* Vt = Kbf + QE;
    unsigned short* Xq = Vt + QE;  // reused as attn_bf after gemm Q
    unsigned short* Xk = Xq + QE;
    unsigned short* Xv = Xk + QE;
    unsigned short* Wqh = Xv + QE;
    unsigned short* Wql = Wqh + WE;
    unsigned short* Wkh = Wql + WE;
    unsigned short* Wkl = Wkh + WE;
    unsigned short* Wvh = Wkl + WE;
    unsigned short* Wvl = Wvh + WE;
    unsigned short* Woh = Wvl + WE;
    unsigned short* Wol = Woh + WE;
    float* m_ws = (float*)(Wol + WE);
    float* l_ws = m_ws + (size_t)Bn * Hn * Sn;
    unsigned short* attn_bf = Xq;

    float* out0 = (float*)d_out;
    float* avg = out0 + (size_t)Bn * Sn * Dn;

    // fold score scale (1/8) and ln->log2 conversion into Q projection
    const float QSC = 0.125f * 1.44269504088896341f;

    cvt_plain3<<<dim3(4096, 3), 256, 0, stream>>>(query, key_, value, Xq, Xk, Xv);
    cvt_split4<<<dim3(512, 4), 256, 0, stream>>>(Wq, Wk, Wv, Wo, Wqh, Wql, Wkh, Wkl,
                                                 Wvh, Wvl, Woh, Wol);

    const dim3 gg(8, 64), bb(256);
    gemm_bf<0><<<gg, bb, 0, stream>>>(Xq, Wqh, Wql, bq, QSC, Qbf, nullptr);
    gemm_bf<0><<<gg, bb, 0, stream>>>(Xk, Wkh, Wkl, bk, 1.0f, Kbf, nullptr);
    gemm_bf<1><<<gg, bb, 0, stream>>>(Xv, Wvh, Wvl, bv, 1.0f, Vt, nullptr);
    flash_fwd<<<dim3(Bn * Hn * (Sn / 64)), bb, 0, stream>>>(Qbf, Kbf, Vt, attn_bf,
                                                            m_ws, l_ws);
    avg_attn_kernel<<<dim3(Bn * 32 * 32), bb, 0, stream>>>(Qbf, Kbf, m_ws, l_ws, avg);
    gemm_bf<2><<<gg, bb, 0, stream>>>(attn_bf, Woh, Wol, bo, 1.0f, nullptr, out0);
}

// Round 9
// 604.466 us; speedup vs baseline: 1.2044x; 1.0965x over previous
//
#include <hip/hip_runtime.h>
#include <hip/hip_bf16.h>

// ---------------------------------------------------------------------------
// InterpretableMultiHeadAttention on MI355X (gfx950)
// B=4, S=2048, D=1024, H=16, Dh=64
//
// Round-9: flash softmax de-serialization.
//   - flash_fwd: fixed-bound softmax (m=8 in log2 domain, ~5.5 sigma) with an
//     EXACT rare fallback (full shfl reduce + rescale) guarded by __any.
//     Removes the 32 per-iteration shfl_xor LDS-pipe chains that made flash
//     latency-bound (r8: 6.6K cyc/iter wall vs ~600 issue). l is accumulated
//     as per-lane partials, reduced once after the k-loop.
//   - avg_attn: K staging double-buffered across heads (proven dbuf pattern).
//   - gemm_bf / cvt: round-8 verbatim (proven).
// ---------------------------------------------------------------------------

#define DEVI __device__ __forceinline__

typedef __attribute__((ext_vector_type(8))) short bf16x8;
typedef __attribute__((ext_vector_type(4))) float f32x4;

#define MFMA_BF16(a, b, c) __builtin_amdgcn_mfma_f32_16x16x32_bf16(a, b, c, 0, 0, 0)

constexpr int Bn = 4;
constexpr int Sn = 2048;
constexpr int Dn = 1024;
constexpr int Hn = 16;

DEVI unsigned short f2bf_rn(float x) {
    unsigned u = __float_as_uint(x);
    u += 0x7fffu + ((u >> 16) & 1u);
    return (unsigned short)(u >> 16);
}
DEVI float bf2f(unsigned short h) { return __uint_as_float(((unsigned)h) << 16); }

// XOR swizzles over 8-elem granules (0 bank conflicts measured r1/r2/r7/r8).
DEVI int swz32(int r, int k) { return r * 32 + ((((k >> 3) ^ r) & 3) << 3) + (k & 7); }
DEVI int swz64(int r, int k) { return r * 64 + ((((k >> 3) ^ r) & 7) << 3) + (k & 7); }

// async global->LDS, 16B per lane; dest = wave-uniform base + lane*16
DEVI void gload16(const unsigned short* g, unsigned short* l) {
    __builtin_amdgcn_global_load_lds(
        (const __attribute__((address_space(1))) unsigned int*)g,
        (__attribute__((address_space(3))) unsigned int*)l, 16, 0, 0);
}

// ---------------------------------------------------------------------------
// P0: plain f32 -> bf16 conversion for query/key/value
// ---------------------------------------------------------------------------
__global__ __launch_bounds__(256) void cvt_plain3(
    const float* __restrict__ a, const float* __restrict__ b, const float* __restrict__ c,
    unsigned short* __restrict__ oa, unsigned short* __restrict__ ob,
    unsigned short* __restrict__ oc)
{
    const float* s = blockIdx.y == 0 ? a : blockIdx.y == 1 ? b : c;
    unsigned short* d = blockIdx.y == 0 ? oa : blockIdx.y == 1 ? ob : oc;
    const size_t i = ((size_t)blockIdx.x * 256 + threadIdx.x) * 8;
    const float4 v0 = *reinterpret_cast<const float4*>(s + i);
    const float4 v1 = *reinterpret_cast<const float4*>(s + i + 4);
    const float* p0 = reinterpret_cast<const float*>(&v0);
    const float* p1 = reinterpret_cast<const float*>(&v1);
    bf16x8 o;
#pragma unroll
    for (int j = 0; j < 4; ++j) {
        o[j] = (short)f2bf_rn(p0[j]);
        o[4 + j] = (short)f2bf_rn(p1[j]);
    }
    *reinterpret_cast<bf16x8*>(d + i) = o;
}

// ---------------------------------------------------------------------------
// P1: split f32 -> (hi,lo) bf16 for the four weight matrices
// ---------------------------------------------------------------------------
__global__ __launch_bounds__(256) void cvt_split4(
    const float* __restrict__ w0, const float* __restrict__ w1,
    const float* __restrict__ w2, const float* __restrict__ w3,
    unsigned short* __restrict__ h0, unsigned short* __restrict__ l0,
    unsigned short* __restrict__ h1, unsigned short* __restrict__ l1,
    unsigned short* __restrict__ h2, unsigned short* __restrict__ l2,
    unsigned short* __restrict__ h3, unsigned short* __restrict__ l3)
{
    const int y = blockIdx.y;
    const float* s = y == 0 ? w0 : y == 1 ? w1 : y == 2 ? w2 : w3;
    unsigned short* dh = y == 0 ? h0 : y == 1 ? h1 : y == 2 ? h2 : h3;
    unsigned short* dl = y == 0 ? l0 : y == 1 ? l1 : y == 2 ? l2 : l3;
    const size_t i = ((size_t)blockIdx.x * 256 + threadIdx.x) * 8;
    const float4 v0 = *reinterpret_cast<const float4*>(s + i);
    const float4 v1 = *reinterpret_cast<const float4*>(s + i + 4);
    const float* p0 = reinterpret_cast<const float*>(&v0);
    const float* p1 = reinterpret_cast<const float*>(&v1);
    bf16x8 oh, ol;
#pragma unroll
    for (int j = 0; j < 4; ++j) {
        unsigned short h = f2bf_rn(p0[j]);
        oh[j] = (short)h;
        ol[j] = (short)f2bf_rn(p0[j] - bf2f(h));
        h = f2bf_rn(p1[j]);
        oh[4 + j] = (short)h;
        ol[4 + j] = (short)f2bf_rn(p1[j] - bf2f(h));
    }
    *reinterpret_cast<bf16x8*>(dh + i) = oh;
    *reinterpret_cast<bf16x8*>(dl + i) = ol;
}

// ---------------------------------------------------------------------------
// GEMM (round-8 verbatim): C = (X*(Whi+Wlo)^T + bias) * oscale
// Tile 128x128, BK=32, gload16 staging. Grid (8,64) = 512 blocks.
// MODE 0: bf16 [B,H,S,64]  MODE 1: bf16 [B,H,64,S] (V^T)  MODE 2: f32 [M,N]
// ---------------------------------------------------------------------------
template <int MODE>
__global__ __launch_bounds__(256) void gemm_bf(
    const unsigned short* __restrict__ Xbf,
    const unsigned short* __restrict__ Whi, const unsigned short* __restrict__ Wlo,
    const float* __restrict__ bias, float oscale,
    unsigned short* __restrict__ o_bf, float* __restrict__ o_f32)
{
    constexpr int K = Dn;
    __shared__ __align__(16) unsigned short sA[128 * 32];
    __shared__ __align__(16) unsigned short sBh[128 * 32];
    __shared__ __align__(16) unsigned short sBl[128 * 32];

    const int tid = threadIdx.x, lane = tid & 63, w = tid >> 6;
    const int row0 = blockIdx.y * 128, col0 = blockIdx.x * 128;
    const int wm = (w >> 1) * 64, wn = (w & 1) * 64;
    const int fr = lane & 15, hi = lane >> 4, kof = hi * 8;

    const int g0 = tid, g1 = tid + 256;
    const int r0 = g0 >> 2, c0 = ((g0 & 3) ^ r0) & 3;
    const int r1 = g1 >> 2, c1 = ((g1 & 3) ^ r1) & 3;

    const unsigned short* pa0 = Xbf + (size_t)(row0 + r0) * K + c0 * 8;
    const unsigned short* pa1 = Xbf + (size_t)(row0 + r1) * K + c1 * 8;
    const unsigned short* pbh0 = Whi + (size_t)(col0 + r0) * K + c0 * 8;
    const unsigned short* pbh1 = Whi + (size_t)(col0 + r1) * K + c1 * 8;
    const unsigned short* pbl0 = Wlo + (size_t)(col0 + r0) * K + c0 * 8;
    const unsigned short* pbl1 = Wlo + (size_t)(col0 + r1) * K + c1 * 8;

    f32x4 acc[4][4] = {};

    for (int k0 = 0; k0 < K; k0 += 32) {
        gload16(pa0 + k0, &sA[(w * 64) * 8]);
        gload16(pa1 + k0, &sA[(256 + w * 64) * 8]);
        gload16(pbh0 + k0, &sBh[(w * 64) * 8]);
        gload16(pbh1 + k0, &sBh[(256 + w * 64) * 8]);
        gload16(pbl0 + k0, &sBl[(w * 64) * 8]);
        gload16(pbl1 + k0, &sBl[(256 + w * 64) * 8]);
        __syncthreads();

        bf16x8 fa[4], fbh[4], fbl[4];
#pragma unroll
        for (int m = 0; m < 4; ++m) fa[m] = *(const bf16x8*)&sA[swz32(wm + m * 16 + fr, kof)];
#pragma unroll
        for (int n = 0; n < 4; ++n) {
            const int ib = swz32(wn + n * 16 + fr, kof);
            fbh[n] = *(const bf16x8*)&sBh[ib];
            fbl[n] = *(const bf16x8*)&sBl[ib];
        }
#pragma unroll
        for (int m = 0; m < 4; ++m)
#pragma unroll
            for (int n = 0; n < 4; ++n) {
                acc[m][n] = MFMA_BF16(fa[m], fbh[n], acc[m][n]);
                acc[m][n] = MFMA_BF16(fa[m], fbl[n], acc[m][n]);
            }
        __syncthreads();
    }

    float bv_[4];
#pragma unroll
    for (int n = 0; n < 4; ++n) bv_[n] = bias[col0 + wn + n * 16 + fr];

#pragma unroll
    for (int m = 0; m < 4; ++m)
#pragma unroll
        for (int n = 0; n < 4; ++n)
#pragma unroll
            for (int r = 0; r < 4; ++r) {
                const int row = row0 + wm + m * 16 + hi * 4 + r;
                const int col = col0 + wn + n * 16 + fr;
                float v = acc[m][n][r] + bv_[n];
                if (MODE == 0) {
                    v *= oscale;
                    const int bb = row >> 11, s = row & 2047;
                    const int hh = col >> 6, dh = col & 63;
                    o_bf[((size_t)(bb * Hn + hh) * Sn + s) * 64 + dh] = f2bf_rn(v);
                } else if (MODE == 1) {
                    const int bb = row >> 11, s = row & 2047;
                    const int hh = col >> 6, dh = col & 63;
                    o_bf[((size_t)(bb * Hn + hh) * 64 + dh) * Sn + s] = f2bf_rn(v);
                } else {
                    o_f32[(size_t)row * Dn + col] = v;
                }
            }
}

// ---------------------------------------------------------------------------
// K2: flash attention. gload16 dbuf staging (r8-proven). Fixed-bound softmax:
// m_r starts at MB=8 (log2 domain); fast path has NO cross-lane ops except one
// __any check; exact fallback (full shfl reduce + rescale) on rare trigger.
// l accumulated as per-lane partials, shfl-reduced once after the k-loop.
// ---------------------------------------------------------------------------
__global__ __launch_bounds__(256) void flash_fwd(
    const unsigned short* __restrict__ Qbf, const unsigned short* __restrict__ Kbf,
    const unsigned short* __restrict__ Vt,
    unsigned short* __restrict__ attn_bf, float* __restrict__ m_ws, float* __restrict__ l_ws)
{
    __shared__ __align__(16) unsigned short kh_l[2][64 * 64];
    __shared__ __align__(16) unsigned short vt_l[2][64 * 64];
    __shared__ __align__(16) unsigned short p_l[4 * 16 * 64];

    const int tid = threadIdx.x, lane = tid & 63, w = tid >> 6;
    const int qt = blockIdx.x & 31;
    const int h = (blockIdx.x >> 5) & 15;
    const int b = blockIdx.x >> 9;
    const int fr = lane & 15, kof = (lane >> 4) * 8;
    const size_t head = (size_t)(b * Hn + h) * Sn;
    const int qbase = qt * 64;
    const int qrow = qbase + w * 16 + fr;

    const int gS0 = w * 64 + lane, gS1 = 256 + w * 64 + lane;
    const int rS0 = gS0 >> 3, cS0 = ((gS0 & 7) ^ rS0) & 7;
    const int rS1 = gS1 >> 3, cS1 = ((gS1 & 7) ^ rS1) & 7;
    const unsigned short* kp0 = Kbf + (head + rS0) * 64 + cS0 * 8;
    const unsigned short* kp1 = Kbf + (head + rS1) * 64 + cS1 * 8;
    const unsigned short* vp0 = Vt + ((size_t)(b * Hn + h) * 64 + rS0) * Sn + cS0 * 8;
    const unsigned short* vp1 = Vt + ((size_t)(b * Hn + h) * 64 + rS1) * Sn + cS1 * 8;

    bf16x8 aq[2];
    {
        const unsigned short* qp = Qbf + (head + qrow) * 64;
        aq[0] = *(const bf16x8*)(qp + kof);
        aq[1] = *(const bf16x8*)(qp + 32 + kof);
    }

    // log2-domain fixed bound (~5.5 sigma of score distribution)
    float m_r[4] = {8.0f, 8.0f, 8.0f, 8.0f};
    float lp[4] = {0.f, 0.f, 0.f, 0.f};  // per-lane partial sums
    f32x4 o[4] = {};
    int cur = 0;

    gload16(kp0, &kh_l[0][(w * 64) * 8]);
    gload16(kp1, &kh_l[0][(256 + w * 64) * 8]);
    gload16(vp0, &vt_l[0][(w * 64) * 8]);
    gload16(vp1, &vt_l[0][(256 + w * 64) * 8]);
    __syncthreads();

    for (int kb = 0; kb < Sn; kb += 64) {
        if (kb + 64 < Sn) {
            const int nb = cur ^ 1;
            gload16(kp0 + (size_t)(kb + 64) * 64, &kh_l[nb][(w * 64) * 8]);
            gload16(kp1 + (size_t)(kb + 64) * 64, &kh_l[nb][(256 + w * 64) * 8]);
            gload16(vp0 + kb + 64, &vt_l[nb][(w * 64) * 8]);
            gload16(vp1 + kb + 64, &vt_l[nb][(256 + w * 64) * 8]);
        }

        f32x4 sc[4] = {};
#pragma unroll
        for (int n = 0; n < 4; ++n) {
            const int kr = n * 16 + fr;
#pragma unroll
            for (int ks = 0; ks < 2; ++ks) {
                const bf16x8 bh = *(const bf16x8*)&kh_l[cur][swz64(kr, ks * 32 + kof)];
                sc[n] = MFMA_BF16(aq[ks], bh, sc[n]);
            }
        }
        // sc in log2 domain (0.125*log2e folded into Q projection)

        // cheap wave-uniform overflow check: any element above its row's bound?
        bool grow = false;
#pragma unroll
        for (int r = 0; r < 4; ++r) {
            const float lm = fmaxf(fmaxf(sc[0][r], sc[1][r]), fmaxf(sc[2][r], sc[3][r]));
            grow = grow || (lm > m_r[r]);
        }
        if (__any((int)grow)) {  // rare (~1e-5 of tiles): exact reduce + rescale
#pragma unroll
            for (int r = 0; r < 4; ++r) {
                float rm = fmaxf(fmaxf(sc[0][r], sc[1][r]), fmaxf(sc[2][r], sc[3][r]));
                rm = fmaxf(rm, __shfl_xor(rm, 1));
                rm = fmaxf(rm, __shfl_xor(rm, 2));
                rm = fmaxf(rm, __shfl_xor(rm, 4));
                rm = fmaxf(rm, __shfl_xor(rm, 8));
                const float mn = fmaxf(m_r[r], rm);
                const float sf = __builtin_amdgcn_exp2f(m_r[r] - mn);
#pragma unroll
                for (int n = 0; n < 4; ++n) o[n][r] *= sf;
                lp[r] *= sf;
                m_r[r] = mn;
            }
        }

#pragma unroll
        for (int n = 0; n < 4; ++n)
#pragma unroll
            for (int r = 0; r < 4; ++r) {
                const float p = __builtin_amdgcn_exp2f(sc[n][r] - m_r[r]);
                lp[r] += p;
                p_l[w * 1024 + swz64((lane >> 4) * 4 + r, n * 16 + fr)] = f2bf_rn(p);
            }

        const bf16x8 pa0 = *(const bf16x8*)&p_l[w * 1024 + swz64(fr, kof)];
        const bf16x8 pa1 = *(const bf16x8*)&p_l[w * 1024 + swz64(fr, 32 + kof)];
#pragma unroll
        for (int n = 0; n < 4; ++n) {
            const bf16x8 bv0 = *(const bf16x8*)&vt_l[cur][swz64(n * 16 + fr, kof)];
            const bf16x8 bv1 = *(const bf16x8*)&vt_l[cur][swz64(n * 16 + fr, 32 + kof)];
            o[n] = MFMA_BF16(pa0, bv0, o[n]);
            o[n] = MFMA_BF16(pa1, bv1, o[n]);
        }
        __syncthreads();
        cur ^= 1;
    }

    // one-time l reduction (order-free sum; rescales were applied to partials)
    float l_r[4];
#pragma unroll
    for (int r = 0; r < 4; ++r) {
        float t = lp[r];
        t += __shfl_xor(t, 1);
        t += __shfl_xor(t, 2);
        t += __shfl_xor(t, 4);
        t += __shfl_xor(t, 8);
        l_r[r] = t;
    }

#pragma unroll
    for (int r = 0; r < 4; ++r) {
        const float inv = 1.f / l_r[r];
        const int row_ = qbase + w * 16 + (lane >> 4) * 4 + r;
#pragma unroll
        for (int n = 0; n < 4; ++n)
            attn_bf[((size_t)(b * Sn + row_)) * Dn + h * 64 + n * 16 + fr] =
                f2bf_rn(o[n][r] * inv);
    }
    if (fr == 0) {
#pragma unroll
        for (int r = 0; r < 4; ++r) {
            const int row_ = qbase + w * 16 + (lane >> 4) * 4 + r;
            m_ws[head + row_] = m_r[r];  // log2 domain
            l_ws[head + row_] = l_r[r];
        }
    }
}

// ---------------------------------------------------------------------------
// K3: avg_attention. Round-8 compute; K staging double-buffered across heads.
// Scores bitwise-identical to flash (same MFMA sequence on same data).
// ---------------------------------------------------------------------------
__global__ __launch_bounds__(256) void avg_attn_kernel(
    const unsigned short* __restrict__ Qbf, const unsigned short* __restrict__ Kbf,
    const float* __restrict__ m_ws, const float* __restrict__ l_ws,
    float* __restrict__ avg)
{
    __shared__ __align__(16) unsigned short kh_l[2][64 * 64];

    const int tid = threadIdx.x, lane = tid & 63, w = tid >> 6;
    const int kt = blockIdx.x & 31;
    const int qt = (blockIdx.x >> 5) & 31;
    const int b = blockIdx.x >> 10;
    const int fr = lane & 15, kof = (lane >> 4) * 8;
    const int qbase = qt * 64, kbase = kt * 64;
    const int qrow = qbase + w * 16 + fr;

    const int gS0 = w * 64 + lane, gS1 = 256 + w * 64 + lane;
    const int rS0 = gS0 >> 3, cS0 = ((gS0 & 7) ^ rS0) & 7;
    const int rS1 = gS1 >> 3, cS1 = ((gS1 & 7) ^ rS1) & 7;

    f32x4 facc[4] = {};
    int cur = 0;

    {
        const size_t hd = (size_t)(b * Hn) * Sn;
        gload16(Kbf + (hd + kbase + rS0) * 64 + cS0 * 8, &kh_l[0][(w * 64) * 8]);
        gload16(Kbf + (hd + kbase + rS1) * 64 + cS1 * 8, &kh_l[0][(256 + w * 64) * 8]);
    }
    __syncthreads();

    for (int h = 0; h < Hn; ++h) {
        if (h + 1 < Hn) {
            const size_t hd = (size_t)(b * Hn + h + 1) * Sn;
            const int nb = cur ^ 1;
            gload16(Kbf + (hd + kbase + rS0) * 64 + cS0 * 8, &kh_l[nb][(w * 64) * 8]);
            gload16(Kbf + (hd + kbase + rS1) * 64 + cS1 * 8, &kh_l[nb][(256 + w * 64) * 8]);
        }
        const size_t head = (size_t)(b * Hn + h) * Sn;
        const unsigned short* qp = Qbf + (head + qrow) * 64;
        const bf16x8 aq0 = *(const bf16x8*)(qp + kof);
        const bf16x8 aq1 = *(const bf16x8*)(qp + 32 + kof);

        f32x4 sc[4] = {};
#pragma unroll
        for (int n = 0; n < 4; ++n) {
            const int kr = n * 16 + fr;
            const bf16x8 bh0 = *(const bf16x8*)&kh_l[cur][swz64(kr, kof)];
            const bf16x8 bh1 = *(const bf16x8*)&kh_l[cur][swz64(kr, 32 + kof)];
            sc[n] = MFMA_BF16(aq0, bh0, sc[n]);
            sc[n] = MFMA_BF16(aq1, bh1, sc[n]);
        }
#pragma unroll
        for (int r = 0; r < 4; ++r) {
            const int row_ = qbase + w * 16 + (lane >> 4) * 4 + r;
            const float mm = m_ws[head + row_];  // log2 domain
            const float li = 0.0625f / l_ws[head + row_];
#pragma unroll
            for (int n = 0; n < 4; ++n)
                facc[n][r] += __builtin_amdgcn_exp2f(sc[n][r] - mm) * li;
        }
        __syncthreads();
        cur ^= 1;
    }

#pragma unroll
    for (int r = 0; r < 4; ++r) {
        const int row_ = qbase + w * 16 + (lane >> 4) * 4 + r;
#pragma unroll
        for (int n = 0; n < 4; ++n)
            avg[((size_t)(b * Sn + row_)) * Sn + kbase + n * 16 + fr] = facc[n][r];
    }
}

// ---------------------------------------------------------------------------
extern "C" void kernel_launch(void* const* d_in, const int* in_sizes, int n_in,
                              void* d_out, int out_size, void* d_ws, size_t ws_size,
                              hipStream_t stream)
{
    const float* query = (const float*)d_in[0];
    const float* key_ = (const float*)d_in[1];
    const float* value = (const float*)d_in[2];
    const float* Wq = (const float*)d_in[3];
    const float* bq = (const float*)d_in[4];
    const float* Wk = (const float*)d_in[5];
    const float* bk = (const float*)d_in[6];
    const float* Wv = (const float*)d_in[7];
    const float* bv = (const float*)d_in[8];
    const float* Wo = (const float*)d_in[9];
    const float* bo = (const float*)d_in[10];

    const size_t QE = (size_t)Bn * Hn * Sn * 64;  // 8,388,608
    const size_t WE = (size_t)Dn * Dn;            // 1,048,576

    unsigned short* Qbf = (unsigned short*)d_ws;
    unsigned short* Kbf = Qbf + QE;
    unsigned short* Vt = Kbf + QE;
    unsigned short* Xq = Vt + QE;  // reused as attn_bf after gemm Q
    unsigned short* Xk = Xq + QE;
    unsigned short* Xv = Xk + QE;
    unsigned short* Wqh = Xv + QE;
    unsigned short* Wql = Wqh + WE;
    unsigned short* Wkh = Wql + WE;
    unsigned short* Wkl = Wkh + WE;
    unsigned short* Wvh = Wkl + WE;
    unsigned short* Wvl = Wvh + WE;
    unsigned short* Woh = Wvl + WE;
    unsigned short* Wol = Woh + WE;
    float* m_ws = (float*)(Wol + WE);
    float* l_ws = m_ws + (size_t)Bn * Hn * Sn;
    unsigned short* attn_bf = Xq;

    float* out0 = (float*)d_out;
    float* avg = out0 + (size_t)Bn * Sn * Dn;

    // fold score scale (1/8) and ln->log2 conversion into Q projection
    const float QSC = 0.125f * 1.44269504088896341f;

    cvt_plain3<<<dim3(4096, 3), 256, 0, stream>>>(query, key_, value, Xq, Xk, Xv);
    cvt_split4<<<dim3(512, 4), 256, 0, stream>>>(Wq, Wk, Wv, Wo, Wqh, Wql, Wkh, Wkl,
                                                 Wvh, Wvl, Woh, Wol);

    const dim3 gg(8, 64), bb(256);
    gemm_bf<0><<<gg, bb, 0, stream>>>(Xq, Wqh, Wql, bq, QSC, Qbf, nullptr);
    gemm_bf<0><<<gg, bb, 0, stream>>>(Xk, Wkh, Wkl, bk, 1.0f, Kbf, nullptr);
    gemm_bf<1><<<gg, bb, 0, stream>>>(Xv, Wvh, Wvl, bv, 1.0f, Vt, nullptr);
    flash_fwd<<<dim3(Bn * Hn * (Sn / 64)), bb, 0, stream>>>(Qbf, Kbf, Vt, attn_bf,
                                                            m_ws, l_ws);
    avg_attn_kernel<<<dim3(Bn * 32 * 32), bb, 0, stream>>>(Qbf, Kbf, m_ws, l_ws, avg);
    gemm_bf<2><<<gg, bb, 0, stream>>>(attn_bf, Woh, Wol, bo, 1.0f, nullptr, out0);
}